// Round 13
// baseline (59.212 us; speedup 1.0000x reference)
//
#include <hip/hip_runtime.h>

// AutoCorrelation attention — 512-thread radix-8^4 FFT.
// B=16, L=4096, D=64, k=24.
// R13 = R12 + bank-conflict fixes: RK2=72 (L3/L4 lane maps hit all 32
// bank-pairs), V1 image staged as aligned float4 from V0+registers.

#define TOPK  24
#define PI2   6.28318530717958647692f
#define SQH   0.70710678118654752440f   // sqrt(2)/2

// LDS layout (bytes). Z float2[4544] = bytes 0..36351.
// V images overlay Z later: V0 floats[0..4095], V1 floats[4096..8191].
#define V1OFF   4096
#define SM_C0   36352                   // float[512]
#define SM_CAND 38400                   // float2[64]
#define SM_PACK 38912                   // float2[25]
#define SM_CNT  39112
#define SM_THR  39116
#define SM_SIZE 39120
#define RK1     568                     // k1 region stride (float2 units)
#define RK2     72                      // k2 region stride within k1 region

__device__ __forceinline__ float2 cmul(float2 a, float2 b) {
  return make_float2(a.x*b.x - a.y*b.y, a.x*b.y + a.y*b.x);
}

__device__ __forceinline__ unsigned fkey(float f) {
  int b = __float_as_int(f);
  return (unsigned)(b ^ ((b >> 31) | 0x80000000));
}

// spectrum swizzle: conflict-free for store lanes (k2,k3) and load lanes (tid)
__device__ __forceinline__ int SPx(int q) { return q ^ ((q >> 6) & 63); }

// 8-point DFT, natural in/out. S=-1 fwd, +1 inv.
template<int S>
__device__ __forceinline__ void fft8(float2* x) {
  const float sg = (float)S;
  float et0r=x[0].x+x[4].x, et0i=x[0].y+x[4].y;
  float et1r=x[0].x-x[4].x, et1i=x[0].y-x[4].y;
  float et2r=x[2].x+x[6].x, et2i=x[2].y+x[6].y;
  float et3r=x[2].x-x[6].x, et3i=x[2].y-x[6].y;
  float E0r=et0r+et2r, E0i=et0i+et2i;
  float E2r=et0r-et2r, E2i=et0i-et2i;
  float E1r=et1r-sg*et3i, E1i=et1i+sg*et3r;
  float E3r=et1r+sg*et3i, E3i=et1i-sg*et3r;
  float ot0r=x[1].x+x[5].x, ot0i=x[1].y+x[5].y;
  float ot1r=x[1].x-x[5].x, ot1i=x[1].y-x[5].y;
  float ot2r=x[3].x+x[7].x, ot2i=x[3].y+x[7].y;
  float ot3r=x[3].x-x[7].x, ot3i=x[3].y-x[7].y;
  float O0r=ot0r+ot2r, O0i=ot0i+ot2i;
  float O2r=ot0r-ot2r, O2i=ot0i-ot2i;
  float O1r=ot1r-sg*ot3i, O1i=ot1i+sg*ot3r;
  float O3r=ot1r+sg*ot3i, O3i=ot1i-sg*ot3r;
  float T1r = SQH*(O1r - sg*O1i), T1i = SQH*(O1i + sg*O1r);
  float T2r = -sg*O2i,            T2i = sg*O2r;
  float T3r = -SQH*(O3r + sg*O3i), T3i = SQH*(sg*O3r - O3i);
  x[0]=make_float2(E0r+O0r, E0i+O0i);  x[4]=make_float2(E0r-O0r, E0i-O0i);
  x[1]=make_float2(E1r+T1r, E1i+T1i);  x[5]=make_float2(E1r-T1r, E1i-T1i);
  x[2]=make_float2(E2r+T2r, E2i+T2i);  x[6]=make_float2(E2r-T2r, E2i-T2i);
  x[3]=make_float2(E3r+T3r, E3i+T3i);  x[7]=make_float2(E3r-T3r, E3i-T3i);
}

__device__ __forceinline__ void twiddle8(float2* x, float ang) {
  float sb, cb; __sincosf(ang, &sb, &cb);
  float2 w1 = make_float2(cb, sb);
  float2 w2 = cmul(w1,w1), w3 = cmul(w2,w1);
  float2 w4 = cmul(w2,w2), w5 = cmul(w3,w2), w6 = cmul(w3,w3), w7 = cmul(w4,w3);
  x[1]=cmul(x[1],w1); x[2]=cmul(x[2],w2); x[3]=cmul(x[3],w3);
  x[4]=cmul(x[4],w4); x[5]=cmul(x[5],w5); x[6]=cmul(x[6],w6);
  x[7]=cmul(x[7],w7);
}

// Q,K,V [B,L,D] -> ZQK interleaved float2 [B,D,L] + Vt [B,D,L]
__global__ __launch_bounds__(256) void transposeQKV(const float* __restrict__ Q,
                                                    const float* __restrict__ K,
                                                    const float* __restrict__ V,
                                                    float2* __restrict__ ZQK,
                                                    float* __restrict__ Vt) {
  __shared__ float tq[64][65];
  __shared__ float tk[64][65];
  __shared__ float tv[64][65];
  const int b = blockIdx.y;
  const int t0 = blockIdx.x << 6;
  const float* Qb = Q + ((size_t)b << 18);
  const float* Kb = K + ((size_t)b << 18);
  const float* Vb = V + ((size_t)b << 18);
  int tx = threadIdx.x & 63, ty = threadIdx.x >> 6;
#pragma unroll
  for (int i = 0; i < 16; ++i) {
    int r = (i << 2) + ty;
    tq[r][tx] = Qb[(size_t)(t0 + r) * 64 + tx];
    tk[r][tx] = Kb[(size_t)(t0 + r) * 64 + tx];
    tv[r][tx] = Vb[(size_t)(t0 + r) * 64 + tx];
  }
  __syncthreads();
  float2* zoutb = ZQK + ((size_t)b << 18);
  float*  voutb = Vt + ((size_t)b << 18);
#pragma unroll
  for (int i = 0; i < 16; ++i) {
    int d = (i << 2) + ty;
    zoutb[(size_t)d * 4096 + t0 + tx] = make_float2(tq[tx][d], tk[tx][d]);
    voutb[(size_t)d * 4096 + t0 + tx] = tv[tx][d];
  }
}

__global__ __launch_bounds__(256) void transpose64(const float* __restrict__ in,
                                                   float* __restrict__ out,
                                                   int R, int C) {
  __shared__ float tile[64][65];
  int tiles_c = C >> 6;
  int tr = blockIdx.x / tiles_c;
  int tc = blockIdx.x - tr * tiles_c;
  const float* inb = in + (size_t)blockIdx.y * R * C;
  float* outb = out + (size_t)blockIdx.y * R * C;
  int tx = threadIdx.x & 63;
  int ty = threadIdx.x >> 6;
  int r0 = tr << 6, c0 = tc << 6;
#pragma unroll
  for (int i = 0; i < 16; ++i) {
    int r = (i << 2) + ty;
    tile[r][tx] = inb[(size_t)(r0 + r) * C + (c0 + tx)];
  }
  __syncthreads();
#pragma unroll
  for (int i = 0; i < 16; ++i) {
    int r = (i << 2) + ty;
    outb[(size_t)(c0 + r) * R + (r0 + tx)] = tile[tx][r];
  }
}

__global__ __launch_bounds__(512, 8) void corr_kernel(const float2* __restrict__ ZQK,
                                                      const float* __restrict__ Vt,
                                                      float* __restrict__ At) {
  __shared__ __align__(16) unsigned char smem[SM_SIZE];
  float2* Z = (float2*)smem;

  const int tid = threadIdx.x;
  const int k1 = tid >> 6;                 // wave index = k1 digit
  const size_t row = (size_t)blockIdx.x << 12;

  float2 x[8];

  // ======== forward FFT: L1 over j (stride 512) ========
#pragma unroll
  for (int j = 0; j < 8; ++j)
    x[j] = ZQK[row + (j << 9) + tid];
  fft8<-1>(x);
  twiddle8(x, -PI2 * (float)tid / 4096.f);
#pragma unroll
  for (int k = 0; k < 8; ++k) Z[k * RK1 + tid] = x[k];   // X1[k1][t]
  __syncthreads();   // (1) cross-wave handoff

  // ---- L2/L3/L4 wave-private (region k1 only) ----
  {
    const int u = tid & 63;
    float2* Zb = Z + k1 * RK1;
#pragma unroll
    for (int a = 0; a < 8; ++a) x[a] = Zb[(a << 6) + u];
    fft8<-1>(x);
    twiddle8(x, -PI2 * (float)u / 512.f);
#pragma unroll
    for (int k = 0; k < 8; ++k) Zb[k * RK2 + u] = x[k];  // X2[k1][k2][u]
  }
  {
    const int k2 = (tid >> 3) & 7, v = tid & 7;
    float2* Zb = Z + k1 * RK1 + k2 * RK2;
#pragma unroll
    for (int b = 0; b < 8; ++b) x[b] = Zb[(b << 3) + v];
    fft8<-1>(x);
    twiddle8(x, -PI2 * (float)v / 64.f);
#pragma unroll
    for (int k = 0; k < 8; ++k) Zb[(k << 3) + v] = x[k]; // X3[k1][k2][k3][v]
  }

  // ---- L4 + spectrum store (SPx swizzle) ----
  const int flo = k1 + (((tid >> 3) & 7) << 3) + ((tid & 7) << 6);
  {
    const int k2 = (tid >> 3) & 7, k3 = tid & 7;
    const float2* Zb = Z + k1 * RK1 + k2 * RK2 + (k3 << 3);
#pragma unroll
    for (int c = 0; c < 8; ++c) x[c] = Zb[c];
    fft8<-1>(x);                       // x[k4] = X[flo + 512*k4]
    __syncthreads(); // (6) all waves' X3 reads done before SP scatter-writes
#pragma unroll
    for (int d = 0; d < 8; ++d) Z[SPx(flo + (d << 9))] = x[d];
  }
  __syncthreads();   // (7) spectrum complete (cross-wave)

  // ======== pointwise P = Qf*conj(Kf)*(1/4N); x[j] = P[512j + tid] ========
  {
    const float scale = 0.25f / 4096.f;
#pragma unroll
    for (int j = 0; j < 8; ++j) {
      int f  = (j << 9) + tid;
      int fp = (4096 - f) & 4095;
      float2 A  = Z[SPx(f)];
      float2 Bv = Z[SPx(fp)];
      float ur = A.x + Bv.x, ui = A.y - Bv.y;
      float vr = A.x - Bv.x, vi = -A.y - Bv.y;
      float xr = ur*vr - ui*vi, xi = ur*vi + ui*vr;
      x[j] = make_float2(-xi * scale, xr * scale);
    }
  }

  // prefetch V row (hidden under inverse FFT)
  float4 v4s[2];
#pragma unroll
  for (int mm = 0; mm < 2; ++mm)
    v4s[mm] = *(const float4*)&Vt[row + (tid << 2) + (mm << 11)];
  __syncthreads();   // (8) pointwise reads done before inverse overwrites Z

  // ======== inverse FFT (mirror, S=+1) ========
  fft8<1>(x);
  twiddle8(x, PI2 * (float)tid / 4096.f);
#pragma unroll
  for (int k = 0; k < 8; ++k) Z[k * RK1 + tid] = x[k];
  __syncthreads();   // (9) cross-wave handoff
  {
    const int u = tid & 63;
    float2* Zb = Z + k1 * RK1;
#pragma unroll
    for (int a = 0; a < 8; ++a) x[a] = Zb[(a << 6) + u];
    fft8<1>(x);
    twiddle8(x, PI2 * (float)u / 512.f);
#pragma unroll
    for (int k = 0; k < 8; ++k) Zb[k * RK2 + u] = x[k];
  }
  {
    const int k2 = (tid >> 3) & 7, v = tid & 7;
    float2* Zb = Z + k1 * RK1 + k2 * RK2;
#pragma unroll
    for (int b = 0; b < 8; ++b) x[b] = Zb[(b << 3) + v];
    fft8<1>(x);
    twiddle8(x, PI2 * (float)v / 64.f);
#pragma unroll
    for (int k = 0; k < 8; ++k) Zb[(k << 3) + v] = x[k];
  }
  float rr[8];
  {
    const int k2 = (tid >> 3) & 7, k3 = tid & 7;
    const float2* Zb = Z + k1 * RK1 + k2 * RK2 + (k3 << 3);
#pragma unroll
    for (int c = 0; c < 8; ++c) x[c] = Zb[c];
    fft8<1>(x);
#pragma unroll
    for (int d = 0; d < 8; ++d) rr[d] = x[d].x;  // Rxx[flo + 512d]
  }
  __syncthreads();   // (14) rr reads done before V staging overwrites Z

  // ======== stage V0 + c0 ========
  float* Vf = (float*)smem;
#pragma unroll
  for (int mm = 0; mm < 2; ++mm) {
    int n0 = (tid << 2) + (mm << 11);
    *(float4*)&Vf[n0] = v4s[mm];                   // V0
  }
  float c0v = rr[0];
#pragma unroll
  for (int d = 1; d < 8; ++d) c0v = fmaxf(c0v, rr[d]);
  ((float*)(smem + SM_C0))[tid] = c0v;
  if (tid == 0) *(int*)(smem + SM_CNT) = 0;
  __syncthreads();   // B1: V0 + c0 visible

  // ======== stage V1 image (aligned float4 from regs + one V0 read) ========
#pragma unroll
  for (int mm = 0; mm < 2; ++mm) {
    int n0 = (tid << 2) + (mm << 11);
    float4 v = v4s[mm];
    float nx = Vf[(n0 + 4) & 4095];                // V0 complete after B1
    *(float4*)&Vf[V1OFF + n0] = make_float4(v.y, v.z, v.w, nx);
  }

  // ======== wave0: ballot binsearch threshold (top-16 key bits) ========
  if (tid < 64) {
    const float* c0b = (const float*)(smem + SM_C0);
    unsigned kk[8];
#pragma unroll
    for (int m = 0; m < 8; ++m) kk[m] = fkey(c0b[tid + (m << 6)]);
    unsigned T = 0;
    for (int b = 31; b >= 16; --b) {
      unsigned T2 = T | (1u << b);
      int c = 0;
#pragma unroll
      for (int m = 0; m < 8; ++m) c += (kk[m] >= T2) ? 1 : 0;
      unsigned long long b0 = __ballot(c & 1);
      unsigned long long b1 = __ballot(c & 2);
      unsigned long long b2 = __ballot(c & 4);
      unsigned long long b3 = __ballot(c & 8);
      int cnt = __popcll(b0) + 2*__popcll(b1) + 4*__popcll(b2) + 8*__popcll(b3);
      if (cnt >= TOPK) T = T2;
    }
    if (tid == 0) {
      float thrF;
      if (T == 0) thrF = -3e38f;
      else {
        int ib = (T & 0x80000000u) ? (int)(T ^ 0x80000000u) : (int)~T;
        thrF = __int_as_float(ib);
      }
      *(float*)(smem + SM_THR) = thrF;
    }
  }
  __syncthreads();   // B2

  // ======== extraction: append (val, idx) with rr >= thr ========
  {
    const float thrF = *(const float*)(smem + SM_THR);
    int* cnt = (int*)(smem + SM_CNT);
    float2* cand = (float2*)(smem + SM_CAND);
#pragma unroll
    for (int d = 0; d < 8; ++d) {
      if (rr[d] >= thrF) {
        int pos = atomicAdd(cnt, 1);
        if (pos < 64)
          cand[pos] = make_float2(rr[d], __int_as_float(flo + (d << 9)));
      }
    }
  }
  __syncthreads();   // B3

  // ======== wave0: bitonic sort 64 desc, softmax, pack ========
  if (tid < 64) {
    const float2* cand = (const float2*)(smem + SM_CAND);
    int NC = *(const int*)(smem + SM_CNT);
    NC = NC < 64 ? NC : 64;
    float v; int ix;
    if (tid < NC) { float2 cc = cand[tid]; v = cc.x; ix = __float_as_int(cc.y); }
    else          { v = -3e38f; ix = 0x7fffffff; }
#pragma unroll
    for (int k = 2; k <= 64; k <<= 1) {
#pragma unroll
      for (int j = k >> 1; j > 0; j >>= 1) {
        float ov = __shfl_xor(v, j);
        int   oi = __shfl_xor(ix, j);
        bool iless  = (tid & j) == 0;
        bool dird   = (tid & k) == 0;
        bool better = (v > ov) || (v == ov && ix < oi);
        bool keep   = ((iless == dird) == better);
        v  = keep ? v  : ov;
        ix = keep ? ix : oi;
      }
    }
    float m0 = __shfl(v, 0);
    float e = (tid < TOPK) ? __expf(v - m0) : 0.f;
    float es = e;
#pragma unroll
    for (int off = 32; off; off >>= 1) es += __shfl_xor(es, off);
    float2* pack = (float2*)(smem + SM_PACK);
    if (tid < TOPK) pack[tid] = make_float2(e, __int_as_float(ix));
    if (tid == 0)   pack[TOPK] = make_float2(es, 0.f);
  }
  __syncthreads();   // B4: pack + V1 visible

  // ======== gather: thread owns float2 column 2*tid, 4 segments of 1024 ====
  const float2* pack = (const float2*)(smem + SM_PACK);
  const float inv = 1.0f / pack[TOPK].x;
  float2 a0 = make_float2(0,0), a1 = a0, a2 = a0, a3 = a0;
  const int o2 = tid << 1;
#pragma unroll 1
  for (int t = 0; t < TOPK; ++t) {
    float2 p_ = pack[t];
    float e  = p_.x;
    int   ik = __float_as_int(p_.y);
    int base = ik & ~1;
    const float* Vb = Vf + ((ik & 1) ? V1OFF : 0);
    int e0 = (o2        + base) & 4095;
    int e1 = (o2 + 1024 + base) & 4095;
    int e2 = (o2 + 2048 + base) & 4095;
    int e3 = (o2 + 3072 + base) & 4095;
    float2 v0 = *(const float2*)&Vb[e0];
    float2 v1 = *(const float2*)&Vb[e1];
    float2 v2 = *(const float2*)&Vb[e2];
    float2 v3 = *(const float2*)&Vb[e3];
    a0.x += e*v0.x; a0.y += e*v0.y;
    a1.x += e*v1.x; a1.y += e*v1.y;
    a2.x += e*v2.x; a2.y += e*v2.y;
    a3.x += e*v3.x; a3.y += e*v3.y;
  }
  *(float2*)&At[row + o2]        = make_float2(a0.x*inv, a0.y*inv);
  *(float2*)&At[row + o2 + 1024] = make_float2(a1.x*inv, a1.y*inv);
  *(float2*)&At[row + o2 + 2048] = make_float2(a2.x*inv, a2.y*inv);
  *(float2*)&At[row + o2 + 3072] = make_float2(a3.x*inv, a3.y*inv);
}

extern "C" void kernel_launch(void* const* d_in, const int* in_sizes, int n_in,
                              void* d_out, int out_size, void* d_ws, size_t ws_size,
                              hipStream_t stream) {
  const float* Q = (const float*)d_in[0];
  const float* K = (const float*)d_in[1];
  const float* V = (const float*)d_in[2];
  float* out = (float*)d_out;
  float* wsf = (float*)d_ws;

  const int B = 16;
  const size_t SLAB = (size_t)4194304;       // B*L*D floats
  float2* ZQK = (float2*)wsf;                // 2*SLAB floats
  float*  Vt  = wsf + 2 * SLAB;
  float*  At  = Vt;   // alias: block i reads Vt row i (to regs) before writing

  dim3 blk(256);
  transposeQKV<<<dim3(64, B), blk, 0, stream>>>(Q, K, V, ZQK, Vt);
  corr_kernel<<<dim3(B * 64), dim3(512), 0, stream>>>(ZQK, Vt, At);
  transpose64<<<dim3(64, B), blk, 0, stream>>>(At, out, 64, 4096);
}

// Round 14
// 57.739 us; speedup vs baseline: 1.0255x; 1.0255x over previous
//
#include <hip/hip_runtime.h>

// AutoCorrelation attention — 256-thread radix-16^3 FFT (R9 champion base).
// R14 = R9 + (a) region stride 272 (L2/L3 bank maps 2-way = free),
// (b) intra-wave barriers dropped in the group-private L2+L3 stretch
//     (region k1 touched only by threads 16k1..16k1+15, one wave; per-wave
//     DS ops are in-order — validated on HW in R12), (c) V1 image staged as
// aligned float4 from registers + one V0 read (R13), (d) no V pads.

#define TOPK  24
#define PI2   6.28318530717958647692f
#define C16_1 0.92387953251128675613f   // cos(pi/8)
#define S16_1 0.38268343236508977173f   // sin(pi/8)
#define C16_2 0.70710678118654752440f   // cos(pi/4)

#define RK    272                       // T1 region stride (float2 units)
// LDS layout (bytes). Z float2[4352] = bytes 0..34815.
// V images overlay Z: V0 floats[0..4095], V1 floats[4096..8191].
#define V1OFF   4096
#define SM_C0   34816                   // float[256]
#define SM_CAND 35840                   // float2[64]
#define SM_PACK 36352                   // float2[25]
#define SM_CNT  36552
#define SM_THR  36556
#define SM_SIZE 36560

__device__ __forceinline__ float2 cmul(float2 a, float2 b) {
  return make_float2(a.x*b.x - a.y*b.y, a.x*b.y + a.y*b.x);
}

__device__ __forceinline__ unsigned fkey(float f) {
  int b = __float_as_int(f);
  return (unsigned)(b ^ ((b >> 31) | 0x80000000));
}

// 16-point DFT, natural order in and out. S=-1 forward, S=+1 inverse.
template<int S>
__device__ __forceinline__ void fft16(float2* x) {
  const float sg = (float)S;
  float2 y[16];
#pragma unroll
  for (int n2 = 0; n2 < 4; ++n2) {
    float2 a = x[n2], b = x[4+n2], c = x[8+n2], d = x[12+n2];
    float t0r=a.x+c.x, t0i=a.y+c.y, t1r=a.x-c.x, t1i=a.y-c.y;
    float t2r=b.x+d.x, t2i=b.y+d.y, t3r=b.x-d.x, t3i=b.y-d.y;
    y[n2*4+0] = make_float2(t0r+t2r, t0i+t2i);
    y[n2*4+2] = make_float2(t0r-t2r, t0i-t2i);
    y[n2*4+1] = make_float2(t1r - sg*t3i, t1i + sg*t3r);
    y[n2*4+3] = make_float2(t1r + sg*t3i, t1i - sg*t3r);
  }
#define CTW(ii, cc, ss) { float2 v=y[ii]; y[ii]=make_float2(v.x*(cc)-v.y*(sg*(ss)), v.x*(sg*(ss))+v.y*(cc)); }
  CTW(5,  C16_1, S16_1)
  CTW(6,  C16_2, C16_2)
  CTW(7,  S16_1, C16_1)
  CTW(9,  C16_2, C16_2)
  { float2 v = y[10]; y[10] = make_float2(-sg*v.y, sg*v.x); }
  CTW(11, -C16_2, C16_2)
  CTW(13, S16_1, C16_1)
  CTW(14, -C16_2, C16_2)
  CTW(15, -C16_1, -S16_1)
#undef CTW
#pragma unroll
  for (int k1 = 0; k1 < 4; ++k1) {
    float2 a = y[k1], b = y[4+k1], c = y[8+k1], d = y[12+k1];
    float t0r=a.x+c.x, t0i=a.y+c.y, t1r=a.x-c.x, t1i=a.y-c.y;
    float t2r=b.x+d.x, t2i=b.y+d.y, t3r=b.x-d.x, t3i=b.y-d.y;
    x[k1+0]  = make_float2(t0r+t2r, t0i+t2i);
    x[k1+8]  = make_float2(t0r-t2r, t0i-t2i);
    x[k1+4]  = make_float2(t1r - sg*t3i, t1i + sg*t3r);
    x[k1+12] = make_float2(t1r + sg*t3i, t1i - sg*t3r);
  }
}

// x[k] *= w^k, k=1..15; powers via depth-4 product tree.
__device__ __forceinline__ void twiddle_chain(float2* x, float ang) {
  float sb, cb; __sincosf(ang, &sb, &cb);
  float2 w1 = make_float2(cb, sb);
  float2 w2 = cmul(w1,w1), w3 = cmul(w1,w2);
  float2 w4 = cmul(w2,w2), w5 = cmul(w2,w3), w6 = cmul(w3,w3), w7 = cmul(w3,w4);
  float2 w8 = cmul(w4,w4), w9 = cmul(w4,w5), w10 = cmul(w5,w5), w11 = cmul(w5,w6);
  float2 w12 = cmul(w6,w6), w13 = cmul(w6,w7), w14 = cmul(w7,w7), w15 = cmul(w7,w8);
  x[1]=cmul(x[1],w1);   x[2]=cmul(x[2],w2);   x[3]=cmul(x[3],w3);
  x[4]=cmul(x[4],w4);   x[5]=cmul(x[5],w5);   x[6]=cmul(x[6],w6);
  x[7]=cmul(x[7],w7);   x[8]=cmul(x[8],w8);   x[9]=cmul(x[9],w9);
  x[10]=cmul(x[10],w10); x[11]=cmul(x[11],w11); x[12]=cmul(x[12],w12);
  x[13]=cmul(x[13],w13); x[14]=cmul(x[14],w14); x[15]=cmul(x[15],w15);
}

// Q,K,V [B,L,D] -> ZQK interleaved float2 [B,D,L] + Vt [B,D,L]
__global__ __launch_bounds__(256) void transposeQKV(const float* __restrict__ Q,
                                                    const float* __restrict__ K,
                                                    const float* __restrict__ V,
                                                    float2* __restrict__ ZQK,
                                                    float* __restrict__ Vt) {
  __shared__ float tq[64][65];
  __shared__ float tk[64][65];
  __shared__ float tv[64][65];
  const int b = blockIdx.y;
  const int t0 = blockIdx.x << 6;
  const float* Qb = Q + ((size_t)b << 18);
  const float* Kb = K + ((size_t)b << 18);
  const float* Vb = V + ((size_t)b << 18);
  int tx = threadIdx.x & 63, ty = threadIdx.x >> 6;
#pragma unroll
  for (int i = 0; i < 16; ++i) {
    int r = (i << 2) + ty;
    tq[r][tx] = Qb[(size_t)(t0 + r) * 64 + tx];
    tk[r][tx] = Kb[(size_t)(t0 + r) * 64 + tx];
    tv[r][tx] = Vb[(size_t)(t0 + r) * 64 + tx];
  }
  __syncthreads();
  float2* zoutb = ZQK + ((size_t)b << 18);
  float*  voutb = Vt + ((size_t)b << 18);
#pragma unroll
  for (int i = 0; i < 16; ++i) {
    int d = (i << 2) + ty;
    zoutb[(size_t)d * 4096 + t0 + tx] = make_float2(tq[tx][d], tk[tx][d]);
    voutb[(size_t)d * 4096 + t0 + tx] = tv[tx][d];
  }
}

__global__ __launch_bounds__(256) void transpose64(const float* __restrict__ in,
                                                   float* __restrict__ out,
                                                   int R, int C) {
  __shared__ float tile[64][65];
  int tiles_c = C >> 6;
  int tr = blockIdx.x / tiles_c;
  int tc = blockIdx.x - tr * tiles_c;
  const float* inb = in + (size_t)blockIdx.y * R * C;
  float* outb = out + (size_t)blockIdx.y * R * C;
  int tx = threadIdx.x & 63;
  int ty = threadIdx.x >> 6;
  int r0 = tr << 6, c0 = tc << 6;
#pragma unroll
  for (int i = 0; i < 16; ++i) {
    int r = (i << 2) + ty;
    tile[r][tx] = inb[(size_t)(r0 + r) * C + (c0 + tx)];
  }
  __syncthreads();
#pragma unroll
  for (int i = 0; i < 16; ++i) {
    int r = (i << 2) + ty;
    outb[(size_t)(c0 + r) * R + (r0 + tx)] = tile[tx][r];
  }
}

__global__ __launch_bounds__(256, 4) void corr_kernel(const float2* __restrict__ ZQK,
                                                      const float* __restrict__ Vt,
                                                      float* __restrict__ At) {
  __shared__ __align__(16) unsigned char smem[SM_SIZE];
  float2* Z = (float2*)smem;

  const int tid = threadIdx.x;
  const int k1 = tid >> 4, bq = tid & 15;   // group role (k1, bq)
  const size_t row = (size_t)blockIdx.x << 12;

  float2 x[16];

  // ======== forward FFT, L1 (global -> regs -> T1 regions) ========
#pragma unroll
  for (int n1 = 0; n1 < 16; ++n1)
    x[n1] = ZQK[row + (n1 << 8) + tid];
  fft16<-1>(x);
  twiddle_chain(x, -PI2 * (float)tid / 4096.f);
#pragma unroll
  for (int k = 0; k < 16; ++k) Z[k * RK + tid] = x[k];
  __syncthreads();   // (1) cross-wave: every thread wrote every region

  // ---- L2 + L3: region k1 touched only by threads 16k1..16k1+15 (one
  //      wave); per-wave DS in-order => no barriers in this stretch ----
  {
#pragma unroll
    for (int a = 0; a < 16; ++a) x[a] = Z[k1 * RK + (a << 4) + bq];
    fft16<-1>(x);
    twiddle_chain(x, -PI2 * (float)bq / 256.f);
#pragma unroll
    for (int cc = 0; cc < 16; ++cc) Z[k1 * RK + (cc << 4) + (bq ^ cc)] = x[cc];
#pragma unroll
    for (int bb = 0; bb < 16; ++bb) x[bb] = Z[k1 * RK + (bq << 4) + (bb ^ bq)];
    fft16<-1>(x);
  }
  __syncthreads();   // (6) all groups' L3 reads done before flat SP writes
  {
    const int bf = k1 + (bq << 4);
#pragma unroll
    for (int d = 0; d < 16; ++d) Z[(bf ^ bq) + (d << 8)] = x[d];
  }
  __syncthreads();   // (7) spectrum complete

  // ======== pointwise P = Qf*conj(Kf) * (1/4N) ========
  {
    const float scale = 0.25f / 4096.f;
#pragma unroll
    for (int f1 = 0; f1 < 16; ++f1) {
      int f  = (f1 << 8) + tid;
      int fp = (4096 - f) & 4095;
      float2 A  = Z[f ^ k1];
      float2 Bv = Z[fp ^ ((fp >> 4) & 15)];
      float ur = A.x + Bv.x, ui = A.y - Bv.y;
      float vr = A.x - Bv.x, vi = -A.y - Bv.y;
      float xr = ur*vr - ui*vi, xi = ur*vi + ui*vr;
      x[f1] = make_float2(-xi * scale, xr * scale);
    }
  }

  // prefetch V row (latency hidden under inverse FFT)
  float4 v4s[4];
#pragma unroll
  for (int mm = 0; mm < 4; ++mm)
    v4s[mm] = *(const float4*)&Vt[row + (tid << 2) + (mm << 10)];
  __syncthreads();   // (8) spectrum reads done before inverse overwrites Z

  // ======== inverse FFT (mirror) ========
  fft16<1>(x);
  twiddle_chain(x, PI2 * (float)tid / 4096.f);
#pragma unroll
  for (int k = 0; k < 16; ++k) Z[k * RK + tid] = x[k];
  __syncthreads();   // (9) cross-wave
  {
#pragma unroll
    for (int a = 0; a < 16; ++a) x[a] = Z[k1 * RK + (a << 4) + bq];
    fft16<1>(x);
    twiddle_chain(x, PI2 * (float)bq / 256.f);
#pragma unroll
    for (int cc = 0; cc < 16; ++cc) Z[k1 * RK + (cc << 4) + (bq ^ cc)] = x[cc];
#pragma unroll
    for (int bb = 0; bb < 16; ++bb) x[bb] = Z[k1 * RK + (bq << 4) + (bb ^ bq)];
    fft16<1>(x);
  }
  float rr[16];
#pragma unroll
  for (int d = 0; d < 16; ++d) rr[d] = x[d].x;   // Rxx[k1 + 16bq + 256d]
  __syncthreads();   // (14) all rr extracted before V staging overwrites Z

  // ======== stage V0 + c0 ========
  float* Vf = (float*)smem;
#pragma unroll
  for (int mm = 0; mm < 4; ++mm)
    *(float4*)&Vf[(tid << 2) + (mm << 10)] = v4s[mm];   // V0
  float c0v = rr[0];
#pragma unroll
  for (int d = 1; d < 16; ++d) c0v = fmaxf(c0v, rr[d]);
  ((float*)(smem + SM_C0))[tid] = c0v;
  if (tid == 0) *(int*)(smem + SM_CNT) = 0;
  __syncthreads();   // B1: V0 + c0 visible

  // ======== stage V1 image (aligned float4 from regs + one V0 read) ========
#pragma unroll
  for (int mm = 0; mm < 4; ++mm) {
    int n0 = (tid << 2) + (mm << 10);
    float4 v = v4s[mm];
    float nx = Vf[(n0 + 4) & 4095];                // V0 complete after B1
    *(float4*)&Vf[V1OFF + n0] = make_float4(v.y, v.z, v.w, nx);
  }

  // ======== wave0: ballot binsearch threshold (top-16 key bits) ========
  if (tid < 64) {
    const float* c0b = (const float*)(smem + SM_C0);
    unsigned kk0 = fkey(c0b[tid]);
    unsigned kk1 = fkey(c0b[tid + 64]);
    unsigned kk2 = fkey(c0b[tid + 128]);
    unsigned kk3 = fkey(c0b[tid + 192]);
    unsigned T = 0;
    for (int b = 31; b >= 16; --b) {
      unsigned T2 = T | (1u << b);
      int c = (kk0 >= T2) + (kk1 >= T2) + (kk2 >= T2) + (kk3 >= T2);
      unsigned long long b0 = __ballot(c & 1);
      unsigned long long b1 = __ballot(c & 2);
      unsigned long long b2 = __ballot(c & 4);
      int cnt = __popcll(b0) + 2 * __popcll(b1) + 4 * __popcll(b2);
      if (cnt >= TOPK) T = T2;
    }
    if (tid == 0) {
      float thrF;
      if (T == 0) thrF = -3e38f;
      else {
        int ib = (T & 0x80000000u) ? (int)(T ^ 0x80000000u) : (int)~T;
        thrF = __int_as_float(ib);
      }
      *(float*)(smem + SM_THR) = thrF;
    }
  }
  __syncthreads();   // B2

  // ======== extraction: append (val, idx) with rr >= thr ========
  {
    const float thrF = *(const float*)(smem + SM_THR);
    int* cnt = (int*)(smem + SM_CNT);
    float2* cand = (float2*)(smem + SM_CAND);
    const int tb = k1 + (bq << 4);
#pragma unroll
    for (int d = 0; d < 16; ++d) {
      if (rr[d] >= thrF) {
        int pos = atomicAdd(cnt, 1);
        if (pos < 64)
          cand[pos] = make_float2(rr[d], __int_as_float(tb + (d << 8)));
      }
    }
  }
  __syncthreads();   // B3

  // ======== wave0: bitonic sort 64 desc, softmax, pack ========
  if (tid < 64) {
    const float2* cand = (const float2*)(smem + SM_CAND);
    int NC = *(const int*)(smem + SM_CNT);
    NC = NC < 64 ? NC : 64;
    float v; int ix;
    if (tid < NC) { float2 cc = cand[tid]; v = cc.x; ix = __float_as_int(cc.y); }
    else          { v = -3e38f; ix = 0x7fffffff; }
#pragma unroll
    for (int k = 2; k <= 64; k <<= 1) {
#pragma unroll
      for (int j = k >> 1; j > 0; j >>= 1) {
        float ov = __shfl_xor(v, j);
        int   oi = __shfl_xor(ix, j);
        bool iless  = (tid & j) == 0;
        bool dird   = (tid & k) == 0;
        bool better = (v > ov) || (v == ov && ix < oi);
        bool keep   = ((iless == dird) == better);
        v  = keep ? v  : ov;
        ix = keep ? ix : oi;
      }
    }
    float m0 = __shfl(v, 0);
    float e = (tid < TOPK) ? __expf(v - m0) : 0.f;
    float es = e;
#pragma unroll
    for (int off = 32; off; off >>= 1) es += __shfl_xor(es, off);
    float2* pack = (float2*)(smem + SM_PACK);
    if (tid < TOPK) pack[tid] = make_float2(e, __int_as_float(ix));
    if (tid == 0)   pack[TOPK] = make_float2(es, 0.f);
  }
  __syncthreads();   // B4: pack + V1 visible

  // ======== gather: thread owns float2 column 2*tid, 8 segments of 512 ====
  const float2* pack = (const float2*)(smem + SM_PACK);
  const float inv = 1.0f / pack[TOPK].x;
  float2 a0 = make_float2(0,0), a1=a0, a2=a0, a3=a0, a4=a0, a5=a0, a6=a0, a7=a0;
  const int o2 = tid << 1;
#pragma unroll 1
  for (int t = 0; t < TOPK; ++t) {
    float2 p_ = pack[t];
    float e  = p_.x;
    int   ik = __float_as_int(p_.y);
    int base = ik & ~1;
    const float* Vb = Vf + ((ik & 1) ? V1OFF : 0);
#define GSTEP(acc, MM) { int e0 = (o2 + (MM << 9) + base) & 4095;             \
    float2 vv = *(const float2*)&Vb[e0];                                      \
    acc.x += e * vv.x; acc.y += e * vv.y; }
    GSTEP(a0, 0) GSTEP(a1, 1) GSTEP(a2, 2) GSTEP(a3, 3)
    GSTEP(a4, 4) GSTEP(a5, 5) GSTEP(a6, 6) GSTEP(a7, 7)
#undef GSTEP
  }
#define WSTEP(acc, MM) { *(float2*)&At[row + o2 + (MM << 9)] =                \
    make_float2(acc.x * inv, acc.y * inv); }
  WSTEP(a0, 0) WSTEP(a1, 1) WSTEP(a2, 2) WSTEP(a3, 3)
  WSTEP(a4, 4) WSTEP(a5, 5) WSTEP(a6, 6) WSTEP(a7, 7)
#undef WSTEP
}

extern "C" void kernel_launch(void* const* d_in, const int* in_sizes, int n_in,
                              void* d_out, int out_size, void* d_ws, size_t ws_size,
                              hipStream_t stream) {
  const float* Q = (const float*)d_in[0];
  const float* K = (const float*)d_in[1];
  const float* V = (const float*)d_in[2];
  float* out = (float*)d_out;
  float* wsf = (float*)d_ws;

  const int B = 16;
  const size_t SLAB = (size_t)4194304;       // B*L*D floats
  float2* ZQK = (float2*)wsf;                // 2*SLAB floats
  float*  Vt  = wsf + 2 * SLAB;
  float*  At  = Vt;   // alias: block i reads Vt row i (to regs) before writing

  dim3 blk(256);
  transposeQKV<<<dim3(64, B), blk, 0, stream>>>(Q, K, V, ZQK, Vt);
  corr_kernel<<<dim3(B * 64), blk, 0, stream>>>(ZQK, Vt, At);
  transpose64<<<dim3(64, B), blk, 0, stream>>>(At, out, 64, 4096);
}

// Round 15
// 55.279 us; speedup vs baseline: 1.0711x; 1.0445x over previous
//
#include <hip/hip_runtime.h>

// AutoCorrelation attention — register-resident 3-level radix-16 FFT (R9
// champion) + shuffle-free top-k (ballot threshold + bitonic sort).
// R15 = R9 verbatim with ONE change: T1 region stride 272 (was 256) so the
// L2-read / L2-write / L3-read lane->bank maps go 4-way -> 2-way (free).
// B=16, L=4096, D=64, k=24.

#define FFT_N 4096
#define TOPK  24
#define PI2   6.28318530717958647692f
#define C16_1 0.92387953251128675613f   // cos(pi/8)
#define S16_1 0.38268343236508977173f   // sin(pi/8)
#define C16_2 0.70710678118654752440f   // cos(pi/4)

#define RK      272                     // T1 region stride (float2 units)
// LDS layout (bytes). Z float2[16*272=4352] = bytes 0..34815 (FFT phase).
// V images (gather phase, disjoint lifetime): V0ext floats[0..4607],
// V1ext floats[4608..9215] = bytes 0..36863.
#define V1OFF   4608                    // float index of V1 image
#define SM_CAND 36864                   // float2[64]
#define SM_C0   37376                   // float[256]
#define SM_PACK 38400                   // float2[25]
#define SM_CNT  38608                   // int
#define SM_THR  38612                   // float
#define SM_SIZE 38624

__device__ __forceinline__ float2 cmul(float2 a, float2 b) {
  return make_float2(a.x*b.x - a.y*b.y, a.x*b.y + a.y*b.x);
}

// monotone float->uint key (order-preserving incl. negatives)
__device__ __forceinline__ unsigned fkey(float f) {
  int b = __float_as_int(f);
  return (unsigned)(b ^ ((b >> 31) | 0x80000000));
}

// 16-point DFT, natural order in and out. S=-1 forward, S=+1 inverse.
template<int S>
__device__ __forceinline__ void fft16(float2* x) {
  const float sg = (float)S;
  float2 y[16];
#pragma unroll
  for (int n2 = 0; n2 < 4; ++n2) {
    float2 a = x[n2], b = x[4+n2], c = x[8+n2], d = x[12+n2];
    float t0r=a.x+c.x, t0i=a.y+c.y, t1r=a.x-c.x, t1i=a.y-c.y;
    float t2r=b.x+d.x, t2i=b.y+d.y, t3r=b.x-d.x, t3i=b.y-d.y;
    y[n2*4+0] = make_float2(t0r+t2r, t0i+t2i);
    y[n2*4+2] = make_float2(t0r-t2r, t0i-t2i);
    y[n2*4+1] = make_float2(t1r - sg*t3i, t1i + sg*t3r);
    y[n2*4+3] = make_float2(t1r + sg*t3i, t1i - sg*t3r);
  }
#define CTW(ii, cc, ss) { float2 v=y[ii]; y[ii]=make_float2(v.x*(cc)-v.y*(sg*(ss)), v.x*(sg*(ss))+v.y*(cc)); }
  CTW(5,  C16_1, S16_1)
  CTW(6,  C16_2, C16_2)
  CTW(7,  S16_1, C16_1)
  CTW(9,  C16_2, C16_2)
  { float2 v = y[10]; y[10] = make_float2(-sg*v.y, sg*v.x); }
  CTW(11, -C16_2, C16_2)
  CTW(13, S16_1, C16_1)
  CTW(14, -C16_2, C16_2)
  CTW(15, -C16_1, -S16_1)
#undef CTW
#pragma unroll
  for (int k1 = 0; k1 < 4; ++k1) {
    float2 a = y[k1], b = y[4+k1], c = y[8+k1], d = y[12+k1];
    float t0r=a.x+c.x, t0i=a.y+c.y, t1r=a.x-c.x, t1i=a.y-c.y;
    float t2r=b.x+d.x, t2i=b.y+d.y, t3r=b.x-d.x, t3i=b.y-d.y;
    x[k1+0]  = make_float2(t0r+t2r, t0i+t2i);
    x[k1+8]  = make_float2(t0r-t2r, t0i-t2i);
    x[k1+4]  = make_float2(t1r - sg*t3i, t1i + sg*t3r);
    x[k1+12] = make_float2(t1r + sg*t3i, t1i - sg*t3r);
  }
}

// x[k] *= w^k, k=1..15; powers via depth-4 product tree.
__device__ __forceinline__ void twiddle_chain(float2* x, float ang) {
  float sb, cb; __sincosf(ang, &sb, &cb);
  float2 w1 = make_float2(cb, sb);
  float2 w2 = cmul(w1,w1), w3 = cmul(w1,w2);
  float2 w4 = cmul(w2,w2), w5 = cmul(w2,w3), w6 = cmul(w3,w3), w7 = cmul(w3,w4);
  float2 w8 = cmul(w4,w4), w9 = cmul(w4,w5), w10 = cmul(w5,w5), w11 = cmul(w5,w6);
  float2 w12 = cmul(w6,w6), w13 = cmul(w6,w7), w14 = cmul(w7,w7), w15 = cmul(w7,w8);
  x[1]=cmul(x[1],w1);   x[2]=cmul(x[2],w2);   x[3]=cmul(x[3],w3);
  x[4]=cmul(x[4],w4);   x[5]=cmul(x[5],w5);   x[6]=cmul(x[6],w6);
  x[7]=cmul(x[7],w7);   x[8]=cmul(x[8],w8);   x[9]=cmul(x[9],w9);
  x[10]=cmul(x[10],w10); x[11]=cmul(x[11],w11); x[12]=cmul(x[12],w12);
  x[13]=cmul(x[13],w13); x[14]=cmul(x[14],w14); x[15]=cmul(x[15],w15);
}

// Q,K,V [B,L,D] -> ZQK interleaved float2 [B,D,L] + Vt [B,D,L]
__global__ __launch_bounds__(256) void transposeQKV(const float* __restrict__ Q,
                                                    const float* __restrict__ K,
                                                    const float* __restrict__ V,
                                                    float2* __restrict__ ZQK,
                                                    float* __restrict__ Vt) {
  __shared__ float tq[64][65];
  __shared__ float tk[64][65];
  __shared__ float tv[64][65];
  const int b = blockIdx.y;
  const int t0 = blockIdx.x << 6;
  const float* Qb = Q + ((size_t)b << 18);
  const float* Kb = K + ((size_t)b << 18);
  const float* Vb = V + ((size_t)b << 18);
  int tx = threadIdx.x & 63, ty = threadIdx.x >> 6;
#pragma unroll
  for (int i = 0; i < 16; ++i) {
    int r = (i << 2) + ty;
    tq[r][tx] = Qb[(size_t)(t0 + r) * 64 + tx];
    tk[r][tx] = Kb[(size_t)(t0 + r) * 64 + tx];
    tv[r][tx] = Vb[(size_t)(t0 + r) * 64 + tx];
  }
  __syncthreads();
  float2* zoutb = ZQK + ((size_t)b << 18);
  float*  voutb = Vt + ((size_t)b << 18);
#pragma unroll
  for (int i = 0; i < 16; ++i) {
    int d = (i << 2) + ty;
    zoutb[(size_t)d * 4096 + t0 + tx] = make_float2(tq[tx][d], tk[tx][d]);
    voutb[(size_t)d * 4096 + t0 + tx] = tv[tx][d];
  }
}

__global__ __launch_bounds__(256) void transpose64(const float* __restrict__ in,
                                                   float* __restrict__ out,
                                                   int R, int C) {
  __shared__ float tile[64][65];
  int tiles_c = C >> 6;
  int tr = blockIdx.x / tiles_c;
  int tc = blockIdx.x - tr * tiles_c;
  const float* inb = in + (size_t)blockIdx.y * R * C;
  float* outb = out + (size_t)blockIdx.y * R * C;
  int tx = threadIdx.x & 63;
  int ty = threadIdx.x >> 6;
  int r0 = tr << 6, c0 = tc << 6;
#pragma unroll
  for (int i = 0; i < 16; ++i) {
    int r = (i << 2) + ty;
    tile[r][tx] = inb[(size_t)(r0 + r) * C + (c0 + tx)];
  }
  __syncthreads();
#pragma unroll
  for (int i = 0; i < 16; ++i) {
    int r = (i << 2) + ty;
    outb[(size_t)(c0 + r) * R + (r0 + tx)] = tile[tx][r];
  }
}

__global__ __launch_bounds__(256, 4) void corr_kernel(const float2* __restrict__ ZQK,
                                                      const float* __restrict__ Vt,
                                                      float* __restrict__ At) {
  __shared__ __align__(16) unsigned char smem[SM_SIZE];
  float2* Z = (float2*)smem;           // FFT workspace, later V images

  const int tid = threadIdx.x;
  const size_t row = (size_t)blockIdx.x << 12;

  float2 x[16];

  // ======== forward FFT of z = q + i*k ========
#pragma unroll
  for (int n1 = 0; n1 < 16; ++n1)
    x[n1] = ZQK[row + (n1 << 8) + tid];
  fft16<-1>(x);
  twiddle_chain(x, -PI2 * (float)tid / 4096.f);
#pragma unroll
  for (int k = 0; k < 16; ++k) Z[k * RK + tid] = x[k];
  __syncthreads();
  {
    const int k1 = tid >> 4, b = tid & 15;
#pragma unroll
    for (int a = 0; a < 16; ++a) x[a] = Z[k1 * RK + (a << 4) + b];
    fft16<-1>(x);
    twiddle_chain(x, -PI2 * (float)b / 256.f);
    __syncthreads();
#pragma unroll
    for (int cc = 0; cc < 16; ++cc) Z[k1 * RK + (cc << 4) + (b ^ cc)] = x[cc];
  }
  __syncthreads();
  {
    const int k1 = tid >> 4, c = tid & 15;
#pragma unroll
    for (int bb = 0; bb < 16; ++bb) x[bb] = Z[k1 * RK + (c << 4) + (bb ^ c)];
    fft16<-1>(x);
    __syncthreads();
    const int bf = k1 + (c << 4);
#pragma unroll
    for (int d = 0; d < 16; ++d) Z[(bf ^ c) + (d << 8)] = x[d];
  }
  __syncthreads();

  // ======== pointwise P = Qf*conj(Kf) * (1/4N) ========
  {
    const float scale = 0.25f / 4096.f;
    const int x1 = tid >> 4;
#pragma unroll
    for (int f1 = 0; f1 < 16; ++f1) {
      int f  = (f1 << 8) + tid;
      int fp = (4096 - f) & 4095;
      float2 A  = Z[f ^ x1];
      float2 Bv = Z[fp ^ ((fp >> 4) & 15)];
      float ur = A.x + Bv.x, ui = A.y - Bv.y;
      float vr = A.x - Bv.x, vi = -A.y - Bv.y;
      float xr = ur*vr - ui*vi, xi = ur*vi + ui*vr;
      x[f1] = make_float2(-xi * scale, xr * scale);
    }
  }

  // prefetch V row (latency hidden under inverse FFT)
  float4 v4s[4];
#pragma unroll
  for (int mm = 0; mm < 4; ++mm)
    v4s[mm] = *(const float4*)&Vt[row + (tid << 2) + (mm << 10)];

  // ======== inverse FFT ========
  fft16<1>(x);
  twiddle_chain(x, PI2 * (float)tid / 4096.f);
  __syncthreads();
#pragma unroll
  for (int k = 0; k < 16; ++k) Z[k * RK + tid] = x[k];
  __syncthreads();
  {
    const int k1 = tid >> 4, b = tid & 15;
#pragma unroll
    for (int a = 0; a < 16; ++a) x[a] = Z[k1 * RK + (a << 4) + b];
    fft16<1>(x);
    twiddle_chain(x, PI2 * (float)b / 256.f);
    __syncthreads();
#pragma unroll
    for (int cc = 0; cc < 16; ++cc) Z[k1 * RK + (cc << 4) + (b ^ cc)] = x[cc];
  }
  __syncthreads();
  float rr[16];
  {
    const int k1 = tid >> 4, c = tid & 15;
#pragma unroll
    for (int bb = 0; bb < 16; ++bb) x[bb] = Z[k1 * RK + (c << 4) + (bb ^ c)];
    fft16<1>(x);
#pragma unroll
    for (int d = 0; d < 16; ++d) rr[d] = x[d].x;   // Rxx[k1 + 16c + 256d]
  }
  __syncthreads();                                 // all Z reads done; Z free

  // ======== stage V0ext + V1ext (512-float wrap pads) + c0 ========
  float* Vf = (float*)smem;
#pragma unroll
  for (int mm = 0; mm < 4; ++mm) {
    int n0 = (tid << 2) + (mm << 10);
    float4 v = v4s[mm];
    *(float4*)&Vf[n0] = v;                         // V0 main
    Vf[V1OFF + ((n0 - 1) & 4095)] = v.x;           // V1[n]=V[(n+1)%N]
    Vf[V1OFF + n0]     = v.y;
    Vf[V1OFF + n0 + 1] = v.z;
    Vf[V1OFF + n0 + 2] = v.w;
  }
  {
    float4 v = v4s[0];
    if (tid < 128) {                               // pads: V*ext[4096+j]
      *(float4*)&Vf[4096 + (tid << 2)] = v;        // V0 pad = V[0..511]
      Vf[V1OFF + 4096 + (tid << 2) + 0] = v.y;     // V1 pad[4t]   = V[4t+1]
      Vf[V1OFF + 4096 + (tid << 2) + 1] = v.z;
      Vf[V1OFF + 4096 + (tid << 2) + 2] = v.w;
    }
    if (tid >= 1 && tid <= 128)
      Vf[V1OFF + 4096 + (tid << 2) - 1] = v.x;     // V1 pad[4t-1] = V[4t]
  }
  float c0v = rr[0];
#pragma unroll
  for (int d = 1; d < 16; ++d) c0v = fmaxf(c0v, rr[d]);
  ((float*)(smem + SM_C0))[tid] = c0v;
  if (tid == 0) *(int*)(smem + SM_CNT) = 0;
  __syncthreads();   // B1

  // ======== wave0: ballot binsearch for threshold (top-16 key bits) ========
  if (tid < 64) {
    const float* c0b = (const float*)(smem + SM_C0);
    unsigned k0 = fkey(c0b[tid]);
    unsigned k1 = fkey(c0b[tid + 64]);
    unsigned k2 = fkey(c0b[tid + 128]);
    unsigned k3 = fkey(c0b[tid + 192]);
    unsigned T = 0;
    for (int b = 31; b >= 16; --b) {
      unsigned T2 = T | (1u << b);
      int c = (k0 >= T2) + (k1 >= T2) + (k2 >= T2) + (k3 >= T2);
      unsigned long long b0 = __ballot(c & 1);
      unsigned long long b1 = __ballot(c & 2);
      unsigned long long b2 = __ballot(c & 4);
      int cnt = __popcll(b0) + 2 * __popcll(b1) + 4 * __popcll(b2);
      if (cnt >= TOPK) T = T2;
    }
    if (tid == 0) {
      float thrF;
      if (T == 0) thrF = -3e38f;
      else {
        int ib = (T & 0x80000000u) ? (int)(T ^ 0x80000000u) : (int)~T;
        thrF = __int_as_float(ib);
      }
      *(float*)(smem + SM_THR) = thrF;
    }
  }
  __syncthreads();   // B2

  // ======== extraction: append (val, idx) with rr >= thr ========
  {
    const float thrF = *(const float*)(smem + SM_THR);
    int* cnt = (int*)(smem + SM_CNT);
    float2* cand = (float2*)(smem + SM_CAND);
    const int tb = (tid >> 4) + ((tid & 15) << 4);
#pragma unroll
    for (int d = 0; d < 16; ++d) {
      if (rr[d] >= thrF) {
        int pos = atomicAdd(cnt, 1);
        if (pos < 64)
          cand[pos] = make_float2(rr[d], __int_as_float(tb + (d << 8)));
      }
    }
  }
  __syncthreads();   // B3

  // ======== wave0: bitonic sort 64 desc (val, idx asc), softmax, pack ========
  if (tid < 64) {
    const float2* cand = (const float2*)(smem + SM_CAND);
    int NC = *(const int*)(smem + SM_CNT);
    NC = NC < 64 ? NC : 64;
    float v; int ix;
    if (tid < NC) { float2 cc = cand[tid]; v = cc.x; ix = __float_as_int(cc.y); }
    else          { v = -3e38f; ix = 0x7fffffff; }
#pragma unroll
    for (int k = 2; k <= 64; k <<= 1) {
#pragma unroll
      for (int j = k >> 1; j > 0; j >>= 1) {
        float ov = __shfl_xor(v, j);
        int   oi = __shfl_xor(ix, j);
        bool iless  = (tid & j) == 0;
        bool dird   = (tid & k) == 0;
        bool better = (v > ov) || (v == ov && ix < oi);
        bool keep   = ((iless == dird) == better);
        v  = keep ? v  : ov;
        ix = keep ? ix : oi;
      }
    }
    float m0 = __shfl(v, 0);
    float e = (tid < TOPK) ? __expf(v - m0) : 0.f;
    float es = e;
#pragma unroll
    for (int off = 32; off; off >>= 1) es += __shfl_xor(es, off);
    float2* pack = (float2*)(smem + SM_PACK);
    if (tid < TOPK) pack[tid] = make_float2(e, __int_as_float(ix));
    if (tid == 0)   pack[TOPK] = make_float2(es, 0.f);
  }
  __syncthreads();   // B4

  // ======== gather: A[l] = inv * sum_t e_t * V[(l + i_t) % N] ========
  const float2* pack = (const float2*)(smem + SM_PACK);
  const float inv = 1.0f / pack[TOPK].x;
  float2 a0 = make_float2(0,0), a1=a0, a2=a0, a3=a0, a4=a0, a5=a0, a6=a0, a7=a0;
  const int lbase = tid << 1;
#pragma unroll 1
  for (int t = 0; t < TOPK; ++t) {
    float2 p_ = pack[t];
    float e  = p_.x;
    int   ik = __float_as_int(p_.y);
    int base = ik & ~1;
    const float* Vb = Vf + ((ik & 1) ? V1OFF : 0);
    int e0 = (lbase        + base) & 4095;
    int e1 = (lbase + 1024 + base) & 4095;
    int e2 = (lbase + 2048 + base) & 4095;
    int e3 = (lbase + 3072 + base) & 4095;
    float2 v00 = *(const float2*)&Vb[e0];
    float2 v01 = *(const float2*)&Vb[e0 + 512];    // pad makes this valid
    float2 v10 = *(const float2*)&Vb[e1];
    float2 v11 = *(const float2*)&Vb[e1 + 512];
    float2 v20 = *(const float2*)&Vb[e2];
    float2 v21 = *(const float2*)&Vb[e2 + 512];
    float2 v30 = *(const float2*)&Vb[e3];
    float2 v31 = *(const float2*)&Vb[e3 + 512];
    a0.x += e*v00.x; a0.y += e*v00.y;
    a1.x += e*v01.x; a1.y += e*v01.y;
    a2.x += e*v10.x; a2.y += e*v10.y;
    a3.x += e*v11.x; a3.y += e*v11.y;
    a4.x += e*v20.x; a4.y += e*v20.y;
    a5.x += e*v21.x; a5.y += e*v21.y;
    a6.x += e*v30.x; a6.y += e*v30.y;
    a7.x += e*v31.x; a7.y += e*v31.y;
  }
  *(float2*)&At[row + lbase]        = make_float2(a0.x*inv, a0.y*inv);
  *(float2*)&At[row + lbase + 512]  = make_float2(a1.x*inv, a1.y*inv);
  *(float2*)&At[row + lbase + 1024] = make_float2(a2.x*inv, a2.y*inv);
  *(float2*)&At[row + lbase + 1536] = make_float2(a3.x*inv, a3.y*inv);
  *(float2*)&At[row + lbase + 2048] = make_float2(a4.x*inv, a4.y*inv);
  *(float2*)&At[row + lbase + 2560] = make_float2(a5.x*inv, a5.y*inv);
  *(float2*)&At[row + lbase + 3072] = make_float2(a6.x*inv, a6.y*inv);
  *(float2*)&At[row + lbase + 3584] = make_float2(a7.x*inv, a7.y*inv);
}

extern "C" void kernel_launch(void* const* d_in, const int* in_sizes, int n_in,
                              void* d_out, int out_size, void* d_ws, size_t ws_size,
                              hipStream_t stream) {
  const float* Q = (const float*)d_in[0];
  const float* K = (const float*)d_in[1];
  const float* V = (const float*)d_in[2];
  float* out = (float*)d_out;
  float* wsf = (float*)d_ws;

  const int B = 16;
  const size_t SLAB = (size_t)4194304;       // B*L*D floats
  float2* ZQK = (float2*)wsf;                // 2*SLAB floats
  float*  Vt  = wsf + 2 * SLAB;
  float*  At  = Vt;   // alias: block i reads Vt row i (to regs) before writing

  dim3 blk(256);
  transposeQKV<<<dim3(64, B), blk, 0, stream>>>(Q, K, V, ZQK, Vt);
  corr_kernel<<<dim3(B * 64), blk, 0, stream>>>(ZQK, Vt, At);
  transpose64<<<dim3(64, B), blk, 0, stream>>>(At, out, 64, 4096);
}